// Round 1
// baseline (1032.537 us; speedup 1.0000x reference)
//
#include <hip/hip_runtime.h>

#define C 512
#define HW 4096
#define EPSV 1e-5f

typedef _Float16 fp16x8 __attribute__((ext_vector_type(8)));
typedef _Float16 fp16x4 __attribute__((ext_vector_type(4)));
typedef float f32x4 __attribute__((ext_vector_type(4)));

// ---- workspace layout (bytes) ----
#define OFF_MC    (0)
#define OFF_RC    (8192)
#define OFF_MS    (16384)
#define OFF_RS    (24576)
#define OFF_BETAF (32768)
#define OFF_V     (40960)
#define OFF_BZ    (49152)
#define OFF_A     (65536)
#define OFF_WZ    (OFF_A + 1048576)
#define OFF_T     (OFF_WZ + 1048576)
#define OFF_XCT   (OFF_T + 65536)
#define OFF_XST   (OFF_XCT + 16777216)
#define OFF_KT    (OFF_XST + 16777216)
#define OFF_HM    (OFF_KT + 16777216)
// total = OFF_HM + 16 MiB ~= 69.3 MB

// ---------------------------------------------------------------------------
// 1) per-(b,c) mean / rstd for content (tensor 0) and style (tensor 1)
// ---------------------------------------------------------------------------
__global__ void stats_kernel(const float* __restrict__ xc, const float* __restrict__ xs,
                             char* __restrict__ ws)
{
    int idx = blockIdx.x;                 // 4096 = 2 * 4 * 512
    int tensor = idx >> 11, rem = idx & 2047;
    const float* src = tensor ? xs : xc;
    float* mean = (float*)(ws + (tensor ? OFF_MS : OFF_MC));
    float* rstd = (float*)(ws + (tensor ? OFF_RS : OFF_RC));
    const float* p = src + (size_t)rem * HW;
    float s = 0.f, ss = 0.f;
    for (int i = threadIdx.x; i < HW; i += 256) { float v = p[i]; s += v; ss += v * v; }
    #pragma unroll
    for (int off = 32; off > 0; off >>= 1) { s += __shfl_down(s, off); ss += __shfl_down(ss, off); }
    __shared__ float red[8];
    int w = threadIdx.x >> 6;
    if ((threadIdx.x & 63) == 0) { red[w * 2] = s; red[w * 2 + 1] = ss; }
    __syncthreads();
    if (threadIdx.x == 0) {
        s = red[0] + red[2] + red[4] + red[6];
        ss = red[1] + red[3] + red[5] + red[7];
        float m = s / (float)HW;
        float var = (ss - s * m) / (float)(HW - 1) + EPSV;   // unbiased (n-1) + EPS
        mean[rem] = m;
        rstd[rem] = rsqrtf(var);
    }
}

// ---------------------------------------------------------------------------
// 2) transpose + f16 cast:  x[b][c][n] (fp32) -> xT[b][n][c] (f16)
// ---------------------------------------------------------------------------
__global__ void transpose_kernel(const float* __restrict__ xc, const float* __restrict__ xs,
                                 char* __restrict__ ws)
{
    int bx = blockIdx.x;                  // 4096 = 2 * 4 * 8 * 64
    int tensor = bx >> 11, b = (bx >> 9) & 3, c0 = ((bx >> 6) & 7) * 64, n0 = (bx & 63) * 64;
    const float* src = tensor ? xs : xc;
    _Float16* dst = (_Float16*)(ws + (tensor ? OFF_XST : OFF_XCT));
    __shared__ _Float16 tile[64][66];
    #pragma unroll
    for (int i = 0; i < 16; i++) {
        int flat = threadIdx.x + i * 256;
        int cR = flat >> 6, nR = flat & 63;
        tile[nR][cR] = (_Float16)src[((size_t)(b * C + c0 + cR)) * HW + n0 + nR];
    }
    __syncthreads();
    #pragma unroll
    for (int i = 0; i < 16; i++) {
        int flat = threadIdx.x + i * 256;
        int nW = flat >> 6, cW = flat & 63;
        dst[((size_t)(b * HW + n0 + nW)) * C + c0 + cW] = tile[nW][cW];
    }
}

// ---------------------------------------------------------------------------
// 3) small precomputes: A = Wf^T Wg, Wz = Wo Wh, betaf, bz = Wo bh
// ---------------------------------------------------------------------------
__global__ void precompute_kernel(const float* __restrict__ Wf, const float* __restrict__ Wg,
                                  const float* __restrict__ Wo, const float* __restrict__ Wh,
                                  const float* __restrict__ bf, const float* __restrict__ bh,
                                  char* __restrict__ ws)
{
    float* A = (float*)(ws + OFF_A);
    float* Wz = (float*)(ws + OFF_WZ);
    float* betaf = (float*)(ws + OFF_BETAF);
    float* bz = (float*)(ws + OFF_BZ);
    const float* mc = (const float*)(ws + OFF_MC);
    const float* rc = (const float*)(ws + OFF_RC);
    int bx = blockIdx.x, t = threadIdx.x;
    if (bx < 64) {                               // A[i][j] = sum_co Wf[co][i]*Wg[co][j]
        int i0 = bx * 8;
        float acc0[8], acc1[8];
        #pragma unroll
        for (int r = 0; r < 8; r++) { acc0[r] = 0.f; acc1[r] = 0.f; }
        for (int co = 0; co < C; co++) {
            float wg0 = Wg[co * C + t], wg1 = Wg[co * C + t + 256];
            #pragma unroll
            for (int r = 0; r < 8; r++) {
                float wf = Wf[co * C + i0 + r];
                acc0[r] += wf * wg0; acc1[r] += wf * wg1;
            }
        }
        #pragma unroll
        for (int r = 0; r < 8; r++) {
            A[(i0 + r) * C + t] = acc0[r];
            A[(i0 + r) * C + t + 256] = acc1[r];
        }
    } else if (bx < 128) {                       // Wz[o][j] = sum_i Wo[o][i]*Wh[i][j]
        int o0 = (bx - 64) * 8;
        float acc0[8], acc1[8];
        #pragma unroll
        for (int r = 0; r < 8; r++) { acc0[r] = 0.f; acc1[r] = 0.f; }
        for (int i = 0; i < C; i++) {
            float wh0 = Wh[i * C + t], wh1 = Wh[i * C + t + 256];
            #pragma unroll
            for (int r = 0; r < 8; r++) {
                float wo = Wo[(o0 + r) * C + i];
                acc0[r] += wo * wh0; acc1[r] += wo * wh1;
            }
        }
        #pragma unroll
        for (int r = 0; r < 8; r++) {
            Wz[(o0 + r) * C + t] = acc0[r];
            Wz[(o0 + r) * C + t + 256] = acc1[r];
        }
    } else if (bx < 136) {                       // betaf[b][co] = bf[co] - sum_i Wf[co][i]*mc*rc
        int g = (bx - 128) * 256 + t, b = g >> 9, co = g & 511;
        float acc = 0.f;
        for (int i = 0; i < C; i++) acc += Wf[co * C + i] * mc[b * C + i] * rc[b * C + i];
        betaf[g] = bf[co] - acc;
    } else {                                     // bz[co] = sum_i Wo[co][i]*bh[i]
        int co = (bx - 136) * 256 + t;
        float acc = 0.f;
        for (int i = 0; i < C; i++) acc += Wo[co * C + i] * bh[i];
        bz[co] = acc;
    }
}

// v[b][j] = rs[b][j] * sum_co betaf[b][co]*Wg[co][j]
__global__ void precompute_v_kernel(const float* __restrict__ Wg, char* __restrict__ ws)
{
    const float* betaf = (const float*)(ws + OFF_BETAF);
    const float* rs = (const float*)(ws + OFF_RS);
    float* v = (float*)(ws + OFF_V);
    int g = blockIdx.x * 256 + threadIdx.x, b = g >> 9, j = g & 511;
    float acc = 0.f;
    for (int co = 0; co < C; co++) acc += betaf[b * C + co] * Wg[co * C + j];
    v[g] = rs[b * C + j] * acc;
}

// ---------------------------------------------------------------------------
// 4) fused prep GEMM:
//    rows 0..511   : Kt[b][m][c] = (diag(rc) A diag(rs) @ xs)[c][m]   (stored transposed, f16)
//    rows 512..1023: Hm[b][co][m] = (Wz @ xs)[co][m] + bz[co]         (f16)
// ---------------------------------------------------------------------------
__global__ void __launch_bounds__(256) prep_gemm_kernel(char* __restrict__ ws)
{
    const float* A = (const float*)(ws + OFF_A);
    const float* Wz = (const float*)(ws + OFF_WZ);
    const float* rc = (const float*)(ws + OFF_RC);
    const float* rs = (const float*)(ws + OFF_RS);
    const float* bz = (const float*)(ws + OFF_BZ);
    const _Float16* __restrict__ xsT = (const _Float16*)(ws + OFF_XST);
    _Float16* __restrict__ Kt = (_Float16*)(ws + OFF_KT);
    _Float16* __restrict__ Hm = (_Float16*)(ws + OFF_HM);

    int bx = blockIdx.x;                 // 1024 = 4b * 8 rowblk * 32 mblk (XCD-swizzled)
    int b = bx & 3, rest = bx >> 2;
    int r128 = rest >> 5, mb = rest & 31;
    int r0 = r128 * 128, m0 = mb * 128;
    int w = threadIdx.x >> 6, lane = threadIdx.x & 63, q = lane >> 4, l16 = lane & 15;
    int wr = (w & 1) * 64, wm = (w >> 1) * 64;
    bool isK = (r0 < 512);
    const float* Asrc = isK ? A : Wz;
    int rbase = (isK ? r0 : r0 - 512) + wr;

    f32x4 zz = {0.f, 0.f, 0.f, 0.f};
    f32x4 acc[4][4];
    #pragma unroll
    for (int rt = 0; rt < 4; rt++)
        #pragma unroll
        for (int mt = 0; mt < 4; mt++) acc[rt][mt] = zz;

    float rcv[4];
    #pragma unroll
    for (int rt = 0; rt < 4; rt++)
        rcv[rt] = isK ? rc[b * C + rbase + rt * 16 + l16] : 1.f;

    for (int ks = 0; ks < 16; ks++) {
        int j0 = ks * 32 + q * 8;
        float rsv[8];
        if (isK) {
            float4 u0 = *(const float4*)&rs[b * C + j0];
            float4 u1 = *(const float4*)&rs[b * C + j0 + 4];
            rsv[0] = u0.x; rsv[1] = u0.y; rsv[2] = u0.z; rsv[3] = u0.w;
            rsv[4] = u1.x; rsv[5] = u1.y; rsv[6] = u1.z; rsv[7] = u1.w;
        } else {
            #pragma unroll
            for (int jj = 0; jj < 8; jj++) rsv[jj] = 1.f;
        }
        fp16x8 afr[4];
        #pragma unroll
        for (int rt = 0; rt < 4; rt++) {
            int row = rbase + rt * 16 + l16;
            float4 a0 = *(const float4*)&Asrc[row * C + j0];
            float4 a1 = *(const float4*)&Asrc[row * C + j0 + 4];
            float av8[8];
            av8[0] = a0.x; av8[1] = a0.y; av8[2] = a0.z; av8[3] = a0.w;
            av8[4] = a1.x; av8[5] = a1.y; av8[6] = a1.z; av8[7] = a1.w;
            float sc = rcv[rt];
            #pragma unroll
            for (int jj = 0; jj < 8; jj++)
                afr[rt][jj] = (_Float16)(isK ? av8[jj] * sc * rsv[jj] : av8[jj]);
        }
        fp16x8 bfr[4];
        #pragma unroll
        for (int mt = 0; mt < 4; mt++)
            bfr[mt] = *(const fp16x8*)&xsT[((size_t)(b * HW + m0 + wm + mt * 16 + l16)) * C + j0];
        #pragma unroll
        for (int rt = 0; rt < 4; rt++)
            #pragma unroll
            for (int mt = 0; mt < 4; mt++)
                acc[rt][mt] = __builtin_amdgcn_mfma_f32_16x16x32_f16(afr[rt], bfr[mt], acc[rt][mt], 0, 0, 0);
    }

    if (isK) {
        #pragma unroll
        for (int rt = 0; rt < 4; rt++)
            #pragma unroll
            for (int mt = 0; mt < 4; mt++) {
                int m = m0 + wm + mt * 16 + l16;
                int cb = r0 + wr + rt * 16 + q * 4;
                fp16x4 h;
                h[0] = (_Float16)acc[rt][mt][0]; h[1] = (_Float16)acc[rt][mt][1];
                h[2] = (_Float16)acc[rt][mt][2]; h[3] = (_Float16)acc[rt][mt][3];
                *(fp16x4*)&Kt[((size_t)(b * HW + m)) * C + cb] = h;
            }
    } else {
        #pragma unroll
        for (int rt = 0; rt < 4; rt++) {
            float bzv[4];
            #pragma unroll
            for (int reg = 0; reg < 4; reg++) bzv[reg] = bz[rbase + rt * 16 + q * 4 + reg];
            #pragma unroll
            for (int mt = 0; mt < 4; mt++) {
                int m = m0 + wm + mt * 16 + l16;
                #pragma unroll
                for (int reg = 0; reg < 4; reg++) {
                    int co = rbase + rt * 16 + q * 4 + reg;
                    Hm[((size_t)(b * C + co)) * HW + m] = (_Float16)(acc[rt][mt][reg] + bzv[reg]);
                }
            }
        }
    }
}

// ---------------------------------------------------------------------------
// 5) t[b][m] = sum_j v[b][j] * xs[b][j][m]   (per-key softmax bias)
// ---------------------------------------------------------------------------
__global__ void t_kernel(const float* __restrict__ xs, char* __restrict__ ws)
{
    const float* v = (const float*)(ws + OFF_V);
    float* tG = (float*)(ws + OFF_T);
    int b = blockIdx.x >> 6, m0 = (blockIdx.x & 63) * 64;   // 256 blocks
    int t = threadIdx.x, ml = t & 63, jq = t >> 6;
    float acc = 0.f;
    for (int j = jq * 128; j < jq * 128 + 128; j++)
        acc += v[b * C + j] * xs[((size_t)(b * C + j)) * HW + m0 + ml];
    __shared__ float red[4][64];
    red[jq][ml] = acc;
    __syncthreads();
    if (t < 64) tG[b * HW + m0 + t] = red[0][t] + red[1][t] + red[2][t] + red[3][t];
}

// ---------------------------------------------------------------------------
// 6) flash attention + residual epilogue
//    block: 32 query rows, 4 waves. wave w: S rows (w&1)*16, m-half (w>>1)*32;
//    PV co-slice w*128. out = P_hat @ Hm^T + bo + content.
// ---------------------------------------------------------------------------
__global__ void __launch_bounds__(256, 2) flash_kernel(const float* __restrict__ xc,
                                                       const float* __restrict__ bo,
                                                       float* __restrict__ out,
                                                       char* __restrict__ ws)
{
    const _Float16* __restrict__ xcT = (const _Float16*)(ws + OFF_XCT);
    const _Float16* __restrict__ Kt = (const _Float16*)(ws + OFF_KT);
    const _Float16* __restrict__ Hm = (const _Float16*)(ws + OFF_HM);
    const float* __restrict__ tG = (const float*)(ws + OFF_T);

    int bx = blockIdx.x;                  // 512 = 4b * 128 nblk, XCD-swizzled
    int b = bx & 3, n0 = (bx >> 2) * 32;
    int tid = threadIdx.x, w = tid >> 6, lane = tid & 63, q = lane >> 4, l16 = lane & 15;

    __shared__ _Float16 Qs[32][520];
    __shared__ _Float16 Ks[64][136];
    __shared__ float Ls[32][65];
    __shared__ _Float16 Ps[32][72];
    __shared__ float alphaS[32];
    __shared__ float smS[32];
    __shared__ float tS[64];

    // stage Q[32][512] f16 (consumed after >=1 barrier below)
    #pragma unroll
    for (int i = 0; i < 8; i++) {
        int g = tid + i * 256;
        int row = g >> 6, ch = g & 63;
        *(fp16x8*)&Qs[row][ch * 8] = *(const fp16x8*)&xcT[((size_t)(b * HW + n0 + row)) * C + ch * 8];
    }

    f32x4 zz = {0.f, 0.f, 0.f, 0.f};
    f32x4 acc[2][8];
    #pragma unroll
    for (int nt = 0; nt < 2; nt++)
        #pragma unroll
        for (int ct = 0; ct < 8; ct++) acc[nt][ct] = zz;

    float mx = -3.0e38f, sm = 0.f;        // valid for tid < 32 (row owners)
    int co0 = w * 128, nt_s = (w & 1) * 16, mh = (w >> 1) * 32;

    for (int it = 0; it < 64; it++) {
        int m0 = it * 64;
        if (tid < 64) tS[tid] = tG[b * HW + m0 + tid];
        f32x4 Lf[2]; Lf[0] = zz; Lf[1] = zz;
        for (int kst = 0; kst < 4; kst++) {
            __syncthreads();
            #pragma unroll
            for (int i = 0; i < 4; i++) {
                int g = tid + i * 256;
                int mr = g >> 4, kc = g & 15;
                *(fp16x8*)&Ks[mr][kc * 8] =
                    *(const fp16x8*)&Kt[((size_t)(b * HW + m0 + mr)) * C + kst * 128 + kc * 8];
            }
            __syncthreads();
            #pragma unroll
            for (int ksi = 0; ksi < 4; ksi++) {
                int kk = ksi * 32 + q * 8;
                fp16x8 afr = *(const fp16x8*)&Qs[nt_s + l16][kst * 128 + kk];
                #pragma unroll
                for (int mi = 0; mi < 2; mi++) {
                    fp16x8 bfr = *(const fp16x8*)&Ks[mh + mi * 16 + l16][kk];
                    Lf[mi] = __builtin_amdgcn_mfma_f32_16x16x32_f16(afr, bfr, Lf[mi], 0, 0, 0);
                }
            }
        }
        // spill logits to LDS (C-layout: col=lane&15 -> m, row=q*4+reg -> n)
        #pragma unroll
        for (int mi = 0; mi < 2; mi++)
            #pragma unroll
            for (int reg = 0; reg < 4; reg++)
                Ls[nt_s + q * 4 + reg][mh + mi * 16 + l16] = Lf[mi][reg];
        __syncthreads();
        // online softmax, one thread per query row
        if (tid < 32) {
            int r = tid;
            float tmax = -3.0e38f;
            for (int j = 0; j < 64; j++) tmax = fmaxf(tmax, Ls[r][j] + tS[j]);
            float mxn = fmaxf(mx, tmax);
            float alpha = __expf(mx - mxn);
            float s = 0.f;
            for (int j = 0; j < 64; j++) {
                float p = __expf(Ls[r][j] + tS[j] - mxn);
                Ps[r][j] = (_Float16)p;
                s += p;
            }
            sm = sm * alpha + s;
            mx = mxn;
            alphaS[r] = alpha;
        }
        __syncthreads();
        // rescale accumulators and accumulate P @ Hm^T
        float av[2][4];
        #pragma unroll
        for (int nt = 0; nt < 2; nt++)
            #pragma unroll
            for (int reg = 0; reg < 4; reg++) av[nt][reg] = alphaS[nt * 16 + q * 4 + reg];
        #pragma unroll
        for (int nt = 0; nt < 2; nt++)
            #pragma unroll
            for (int ct = 0; ct < 8; ct++)
                #pragma unroll
                for (int reg = 0; reg < 4; reg++) acc[nt][ct][reg] *= av[nt][reg];
        #pragma unroll
        for (int ksi = 0; ksi < 2; ksi++) {
            int kk = ksi * 32 + q * 8;
            fp16x8 a0 = *(const fp16x8*)&Ps[l16][kk];
            fp16x8 a1 = *(const fp16x8*)&Ps[16 + l16][kk];
            #pragma unroll
            for (int ct = 0; ct < 8; ct++) {
                fp16x8 bfr = *(const fp16x8*)&Hm[((size_t)(b * C + co0 + ct * 16 + l16)) * HW + m0 + kk];
                acc[0][ct] = __builtin_amdgcn_mfma_f32_16x16x32_f16(a0, bfr, acc[0][ct], 0, 0, 0);
                acc[1][ct] = __builtin_amdgcn_mfma_f32_16x16x32_f16(a1, bfr, acc[1][ct], 0, 0, 0);
            }
        }
    }

    if (tid < 32) smS[tid] = 1.f / sm;
    __syncthreads();
    float sv[2][4];
    #pragma unroll
    for (int nt = 0; nt < 2; nt++)
        #pragma unroll
        for (int reg = 0; reg < 4; reg++) sv[nt][reg] = smS[nt * 16 + q * 4 + reg];
    #pragma unroll
    for (int nt = 0; nt < 2; nt++)
        #pragma unroll
        for (int ct = 0; ct < 8; ct++) {
            int co = co0 + ct * 16 + l16;
            size_t base = ((size_t)(b * C + co)) * HW + n0 + nt * 16 + q * 4;
            float4 cv = *(const float4*)&xc[base];
            float bov = bo[co];
            float4 o;
            o.x = acc[nt][ct][0] * sv[nt][0] + bov + cv.x;
            o.y = acc[nt][ct][1] * sv[nt][1] + bov + cv.y;
            o.z = acc[nt][ct][2] * sv[nt][2] + bov + cv.z;
            o.w = acc[nt][ct][3] * sv[nt][3] + bov + cv.w;
            *(float4*)&out[base] = o;
        }
}

// ---------------------------------------------------------------------------
extern "C" void kernel_launch(void* const* d_in, const int* in_sizes, int n_in,
                              void* d_out, int out_size, void* d_ws, size_t ws_size,
                              hipStream_t stream)
{
    const float* content = (const float*)d_in[0];
    const float* style   = (const float*)d_in[1];
    const float* Wf = (const float*)d_in[2];
    const float* bf = (const float*)d_in[3];
    const float* Wg = (const float*)d_in[4];
    // d_in[5] = bg: provably unused (softmax row-constant)
    const float* Wh = (const float*)d_in[6];
    const float* bh = (const float*)d_in[7];
    const float* Wo = (const float*)d_in[8];
    const float* bo = (const float*)d_in[9];
    float* out = (float*)d_out;
    char* ws = (char*)d_ws;

    stats_kernel<<<4096, 256, 0, stream>>>(content, style, ws);
    transpose_kernel<<<4096, 256, 0, stream>>>(content, style, ws);
    precompute_kernel<<<138, 256, 0, stream>>>(Wf, Wg, Wo, Wh, bf, bh, ws);
    precompute_v_kernel<<<8, 256, 0, stream>>>(Wg, ws);
    prep_gemm_kernel<<<1024, 256, 0, stream>>>(ws);
    t_kernel<<<256, 256, 0, stream>>>(style, ws);
    flash_kernel<<<512, 256, 0, stream>>>(content, bo, out, ws);
}